// Round 1
// baseline (212.072 us; speedup 1.0000x reference)
//
#include <hip/hip_runtime.h>
#include <hip/hip_bf16.h>
#include <stdint.h>

typedef __attribute__((ext_vector_type(4))) float f32x4;
typedef __attribute__((ext_vector_type(8))) short bf16x8;
typedef unsigned short u16;

#define T_TOK   2048
#define D_DIM   2048
#define DFF_DIM 1024
#define NEXP    8
#define TOPK    2
#define NROWS   (T_TOK * TOPK)   // 4096
#define BM      128
#define BK      64
#define MAX_MB  40               // sum ceil(Mg/128) <= 4096/128 + 7 = 39

__device__ __forceinline__ u16 f2bf(float f) {
    union { float f; uint32_t u; } v; v.f = f;
    return (u16)((v.u + 0x7FFFu + ((v.u >> 16) & 1u)) >> 16);
}

__device__ __forceinline__ bf16x8 lds_read8(const u16* base, int row, int inner) {
    // tile is [128 rows][64 bf16 = 128 B]; XOR swizzle within the row's 128B
    int off = row * 128 + (inner ^ ((row & 7) << 4));
    return *(const bf16x8*)((const char*)base + off);
}

// ---------------- routing: bucket (token,k) pairs by expert, build schedule ---
__global__ void route_kernel(const int* __restrict__ topk_ids,
                             const float* __restrict__ topk_w,
                             int* __restrict__ sched,        // [0]=nmb, then {e,m0,mlen}*
                             int* __restrict__ row_token,
                             float* __restrict__ row_w) {
    __shared__ int cnt[NEXP], off[NEXP], cur[NEXP];
    const int tid = threadIdx.x;
    if (tid < NEXP) cnt[tid] = 0;
    __syncthreads();
    for (int p = tid; p < NROWS; p += blockDim.x)
        atomicAdd(&cnt[topk_ids[p]], 1);
    __syncthreads();
    if (tid == 0) {
        int acc = 0, mb = 0;
        for (int e = 0; e < NEXP; ++e) {
            off[e] = acc;
            int c = cnt[e];
            for (int m0 = 0; m0 < c; m0 += BM) {
                sched[1 + 3 * mb] = e;
                sched[2 + 3 * mb] = acc + m0;
                sched[3 + 3 * mb] = (c - m0 < BM) ? (c - m0) : BM;
                ++mb;
            }
            acc += c;
        }
        sched[0] = mb;
    }
    if (tid < NEXP) cur[tid] = 0;
    __syncthreads();
    for (int p = tid; p < NROWS; p += blockDim.x) {
        int e = topk_ids[p];
        int slot = off[e] + atomicAdd(&cur[e], 1);
        row_token[slot] = p / TOPK;
        row_w[slot]     = topk_w[p];
    }
}

// ---------------- GEMM1: gathered X @ w1_e^T, fused silu*up -> H (bf16) ------
__global__ __launch_bounds__(256, 2)
void gemm1_kernel(const float* __restrict__ X, const float* __restrict__ w1,
                  const int* __restrict__ sched, const int* __restrict__ row_token,
                  u16* __restrict__ H) {
    __shared__ u16 lA[2][BM * BK];
    __shared__ u16 lB[2][BM * BK];

    const int mb = blockIdx.y;
    if (mb >= sched[0]) return;
    const int e    = sched[1 + 3 * mb];
    const int m0   = sched[2 + 3 * mb];
    const int mlen = sched[3 + 3 * mb];
    const int n0   = blockIdx.x * 64;     // h-column base (gate col; up col = DFF+)

    const int tid  = threadIdx.x;
    const int lane = tid & 63;
    const int wave = tid >> 6;
    const int wm = wave >> 1, wn = wave & 1;
    const int lr = lane & 15, lk = lane >> 4;

    // per-thread staging chunks: 1024 chunks = 128 rows x 8 col-groups of 8
    const float* aptr[4];
    const float* bptr[4];
    int wroff[4];
#pragma unroll
    for (int i = 0; i < 4; ++i) {
        int chunk = tid + i * 256;
        int row = chunk >> 3, c8 = chunk & 7;
        int grow = m0 + row; if (grow > NROWS - 1) grow = NROWS - 1;
        int tok = row_token[grow];
        aptr[i] = X + (size_t)tok * D_DIM + c8 * 8;
        int gcol = (row < 64) ? (n0 + row) : (DFF_DIM + n0 + (row - 64));
        bptr[i] = w1 + ((size_t)e * (2 * DFF_DIM) + gcol) * D_DIM + c8 * 8;
        wroff[i] = row * 128 + ((c8 * 16) ^ ((row & 7) << 4));
    }

    f32x4 ra[4][2], rb[4][2];
    f32x4 accg[4][2], accu[4][2];
#pragma unroll
    for (int m = 0; m < 4; ++m)
#pragma unroll
        for (int n = 0; n < 2; ++n) {
            accg[m][n] = (f32x4){0.f, 0.f, 0.f, 0.f};
            accu[m][n] = (f32x4){0.f, 0.f, 0.f, 0.f};
        }

    // prologue: load+write tile 0
#pragma unroll
    for (int i = 0; i < 4; ++i) {
        ra[i][0] = *(const f32x4*)(aptr[i]);
        ra[i][1] = *(const f32x4*)(aptr[i] + 4);
        rb[i][0] = *(const f32x4*)(bptr[i]);
        rb[i][1] = *(const f32x4*)(bptr[i] + 4);
    }
#pragma unroll
    for (int i = 0; i < 4; ++i) {
        bf16x8 va, vb;
#pragma unroll
        for (int j = 0; j < 4; ++j) {
            va[j] = (short)f2bf(ra[i][0][j]); va[j + 4] = (short)f2bf(ra[i][1][j]);
            vb[j] = (short)f2bf(rb[i][0][j]); vb[j + 4] = (short)f2bf(rb[i][1][j]);
        }
        *(bf16x8*)((char*)lA[0] + wroff[i]) = va;
        *(bf16x8*)((char*)lB[0] + wroff[i]) = vb;
    }
    __syncthreads();

    int cur = 0;
    const int KT = D_DIM / BK;   // 32
    for (int kt = 0; kt < KT; ++kt) {
        if (kt + 1 < KT) {       // issue next tile's global loads (hidden under MFMA)
            int k0 = (kt + 1) * BK;
#pragma unroll
            for (int i = 0; i < 4; ++i) {
                ra[i][0] = *(const f32x4*)(aptr[i] + k0);
                ra[i][1] = *(const f32x4*)(aptr[i] + k0 + 4);
                rb[i][0] = *(const f32x4*)(bptr[i] + k0);
                rb[i][1] = *(const f32x4*)(bptr[i] + k0 + 4);
            }
        }
#pragma unroll
        for (int ks = 0; ks < 2; ++ks) {
            int inner = ks * 64 + lk * 16;
            bf16x8 af[4], bg[2], bu[2];
#pragma unroll
            for (int m = 0; m < 4; ++m)
                af[m] = lds_read8(lA[cur], wm * 64 + m * 16 + lr, inner);
#pragma unroll
            for (int n = 0; n < 2; ++n) {
                bg[n] = lds_read8(lB[cur], wn * 32 + n * 16 + lr, inner);
                bu[n] = lds_read8(lB[cur], 64 + wn * 32 + n * 16 + lr, inner);
            }
#pragma unroll
            for (int m = 0; m < 4; ++m)
#pragma unroll
                for (int n = 0; n < 2; ++n) {
                    accg[m][n] = __builtin_amdgcn_mfma_f32_16x16x32_bf16(af[m], bg[n], accg[m][n], 0, 0, 0);
                    accu[m][n] = __builtin_amdgcn_mfma_f32_16x16x32_bf16(af[m], bu[n], accu[m][n], 0, 0, 0);
                }
        }
        __syncthreads();
        if (kt + 1 < KT) {
#pragma unroll
            for (int i = 0; i < 4; ++i) {
                bf16x8 va, vb;
#pragma unroll
                for (int j = 0; j < 4; ++j) {
                    va[j] = (short)f2bf(ra[i][0][j]); va[j + 4] = (short)f2bf(ra[i][1][j]);
                    vb[j] = (short)f2bf(rb[i][0][j]); vb[j + 4] = (short)f2bf(rb[i][1][j]);
                }
                *(bf16x8*)((char*)lA[cur ^ 1] + wroff[i]) = va;
                *(bf16x8*)((char*)lB[cur ^ 1] + wroff[i]) = vb;
            }
        }
        __syncthreads();
        cur ^= 1;
    }

    // epilogue: h = silu(gate) * up   (C/D layout: col=lane&15, row=(lane>>4)*4+r)
#pragma unroll
    for (int m = 0; m < 4; ++m)
#pragma unroll
        for (int n = 0; n < 2; ++n)
#pragma unroll
            for (int r = 0; r < 4; ++r) {
                int rloc = wm * 64 + m * 16 + (lane >> 4) * 4 + r;
                if (rloc < mlen) {
                    int col = wn * 32 + n * 16 + lr;
                    float g = accg[m][n][r], u = accu[m][n][r];
                    float h = (g / (1.f + __expf(-g))) * u;
                    H[(size_t)(m0 + rloc) * DFF_DIM + n0 + col] = f2bf(h);
                }
            }
}

// ---------------- GEMM2: H @ w2_e^T, scale by route weight, atomicAdd to out -
__global__ __launch_bounds__(256, 2)
void gemm2_kernel(const u16* __restrict__ H, const float* __restrict__ w2,
                  const int* __restrict__ sched, const int* __restrict__ row_token,
                  const float* __restrict__ row_w, float* __restrict__ out) {
    __shared__ u16 lA[2][BM * BK];
    __shared__ u16 lB[2][BM * BK];

    const int mb = blockIdx.y;
    if (mb >= sched[0]) return;
    const int e    = sched[1 + 3 * mb];
    const int m0   = sched[2 + 3 * mb];
    const int mlen = sched[3 + 3 * mb];
    const int n0   = blockIdx.x * 128;

    const int tid  = threadIdx.x;
    const int lane = tid & 63;
    const int wave = tid >> 6;
    const int wm = wave >> 1, wn = wave & 1;
    const int lr = lane & 15, lk = lane >> 4;

    const u16*   aptr[4];
    const float* bptr[4];
    int wroff[4];
#pragma unroll
    for (int i = 0; i < 4; ++i) {
        int chunk = tid + i * 256;
        int row = chunk >> 3, c8 = chunk & 7;
        int grow = m0 + row; if (grow > NROWS - 1) grow = NROWS - 1;
        aptr[i] = H + (size_t)grow * DFF_DIM + c8 * 8;
        bptr[i] = w2 + ((size_t)e * D_DIM + (n0 + row)) * DFF_DIM + c8 * 8;
        wroff[i] = row * 128 + ((c8 * 16) ^ ((row & 7) << 4));
    }

    bf16x8 rah[4];
    f32x4  rb[4][2];
    f32x4  acc[4][4];
#pragma unroll
    for (int m = 0; m < 4; ++m)
#pragma unroll
        for (int n = 0; n < 4; ++n) acc[m][n] = (f32x4){0.f, 0.f, 0.f, 0.f};

#pragma unroll
    for (int i = 0; i < 4; ++i) {
        rah[i]   = *(const bf16x8*)(aptr[i]);
        rb[i][0] = *(const f32x4*)(bptr[i]);
        rb[i][1] = *(const f32x4*)(bptr[i] + 4);
    }
#pragma unroll
    for (int i = 0; i < 4; ++i) {
        bf16x8 vb;
#pragma unroll
        for (int j = 0; j < 4; ++j) {
            vb[j] = (short)f2bf(rb[i][0][j]); vb[j + 4] = (short)f2bf(rb[i][1][j]);
        }
        *(bf16x8*)((char*)lA[0] + wroff[i]) = rah[i];
        *(bf16x8*)((char*)lB[0] + wroff[i]) = vb;
    }
    __syncthreads();

    int cur = 0;
    const int KT = DFF_DIM / BK;   // 16
    for (int kt = 0; kt < KT; ++kt) {
        if (kt + 1 < KT) {
            int k0 = (kt + 1) * BK;
#pragma unroll
            for (int i = 0; i < 4; ++i) {
                rah[i]   = *(const bf16x8*)(aptr[i] + k0);
                rb[i][0] = *(const f32x4*)(bptr[i] + k0);
                rb[i][1] = *(const f32x4*)(bptr[i] + k0 + 4);
            }
        }
#pragma unroll
        for (int ks = 0; ks < 2; ++ks) {
            int inner = ks * 64 + lk * 16;
            bf16x8 af[4], bfr[4];
#pragma unroll
            for (int m = 0; m < 4; ++m)
                af[m] = lds_read8(lA[cur], wm * 64 + m * 16 + lr, inner);
#pragma unroll
            for (int n = 0; n < 4; ++n)
                bfr[n] = lds_read8(lB[cur], wn * 64 + n * 16 + lr, inner);
#pragma unroll
            for (int m = 0; m < 4; ++m)
#pragma unroll
                for (int n = 0; n < 4; ++n)
                    acc[m][n] = __builtin_amdgcn_mfma_f32_16x16x32_bf16(af[m], bfr[n], acc[m][n], 0, 0, 0);
        }
        __syncthreads();
        if (kt + 1 < KT) {
#pragma unroll
            for (int i = 0; i < 4; ++i) {
                bf16x8 vb;
#pragma unroll
                for (int j = 0; j < 4; ++j) {
                    vb[j] = (short)f2bf(rb[i][0][j]); vb[j + 4] = (short)f2bf(rb[i][1][j]);
                }
                *(bf16x8*)((char*)lA[cur ^ 1] + wroff[i]) = rah[i];
                *(bf16x8*)((char*)lB[cur ^ 1] + wroff[i]) = vb;
            }
        }
        __syncthreads();
        cur ^= 1;
    }

#pragma unroll
    for (int m = 0; m < 4; ++m)
#pragma unroll
        for (int n = 0; n < 4; ++n)
#pragma unroll
            for (int r = 0; r < 4; ++r) {
                int rloc = wm * 64 + m * 16 + (lane >> 4) * 4 + r;
                if (rloc < mlen) {
                    int grow = m0 + rloc;
                    int tok  = row_token[grow];
                    float w  = row_w[grow];
                    int col  = wn * 64 + n * 16 + lr;
                    atomicAdd(&out[(size_t)tok * D_DIM + n0 + col], acc[m][n][r] * w);
                }
            }
}

extern "C" void kernel_launch(void* const* d_in, const int* in_sizes, int n_in,
                              void* d_out, int out_size, void* d_ws, size_t ws_size,
                              hipStream_t stream) {
    const float* X  = (const float*)d_in[0];
    const float* w1 = (const float*)d_in[1];
    const float* w2 = (const float*)d_in[2];
    const float* tw = (const float*)d_in[3];
    const int*   ti = (const int*)d_in[4];

    // workspace layout (~8.45 MB total)
    int*   sched     = (int*)d_ws;                                   // 121 ints
    int*   row_token = (int*)((char*)d_ws + 512);                    // 4096 ints
    float* row_w     = (float*)((char*)d_ws + 512 + 4 * NROWS);      // 4096 f32
    u16*   H         = (u16*)((char*)d_ws + 65536);                  // 4096x1024 bf16

    route_kernel<<<1, 256, 0, stream>>>(ti, tw, sched, row_token, row_w);
    hipMemsetAsync(d_out, 0, (size_t)out_size * sizeof(float), stream);
    gemm1_kernel<<<dim3(DFF_DIM / 64, MAX_MB), 256, 0, stream>>>(X, w1, sched, row_token, H);
    gemm2_kernel<<<dim3(D_DIM / 128, MAX_MB), 256, 0, stream>>>(H, w2, sched, row_token, row_w, (float*)d_out);
}

// Round 2
// 161.714 us; speedup vs baseline: 1.3114x; 1.3114x over previous
//
#include <hip/hip_runtime.h>
#include <hip/hip_bf16.h>
#include <stdint.h>

typedef __attribute__((ext_vector_type(4))) float f32x4;
typedef __attribute__((ext_vector_type(8))) short bf16x8;
typedef unsigned short u16;

#define T_TOK   2048
#define D_DIM   2048
#define DFF_DIM 1024
#define NEXP    8
#define TOPK    2
#define NROWS   (T_TOK * TOPK)   // 4096
#define BM      128
#define BK      64
#define MAX_MB  40               // sum ceil(Mg/128) <= 4096/128 + 7 = 39

__device__ __forceinline__ u16 f2bf(float f) {
    union { float f; uint32_t u; } v; v.f = f;
    return (u16)((v.u + 0x7FFFu + ((v.u >> 16) & 1u)) >> 16);
}

__device__ __forceinline__ void gll16(const u16* gsrc, const u16* lds) {
    // async global->LDS, 16B/lane; LDS dest = wave-uniform base + lane*16
    __builtin_amdgcn_global_load_lds(
        (const __attribute__((address_space(1))) uint32_t*)gsrc,
        (__attribute__((address_space(3))) uint32_t*)lds, 16, 0, 0);
}

__device__ __forceinline__ bf16x8 lds_read8_lin(const u16* base, int row, int inner) {
    return *(const bf16x8*)((const char*)base + row * 128 + inner);
}
__device__ __forceinline__ bf16x8 lds_read8_swz(const u16* base, int row, int inner) {
    int off = row * 128 + (inner ^ ((row & 7) << 4));
    return *(const bf16x8*)((const char*)base + off);
}

// ---------------- X -> bf16 prepass ------------------------------------------
__global__ void cvt_x_kernel(const float* __restrict__ X, u16* __restrict__ Xb) {
    int idx = (blockIdx.x * 256 + threadIdx.x) * 8;
    f32x4 a = *(const f32x4*)(X + idx);
    f32x4 b = *(const f32x4*)(X + idx + 4);
    bf16x8 v;
#pragma unroll
    for (int j = 0; j < 4; ++j) { v[j] = (short)f2bf(a[j]); v[j + 4] = (short)f2bf(b[j]); }
    *(bf16x8*)(Xb + idx) = v;
}

// ---------------- routing: bucket (token,k) pairs by expert ------------------
__global__ void route_kernel(const int* __restrict__ topk_ids,
                             const float* __restrict__ topk_w,
                             int* __restrict__ sched,        // [0]=nmb, then {e,m0,mlen}*
                             int* __restrict__ row_token,
                             float* __restrict__ row_w) {
    __shared__ int cnt[NEXP], off[NEXP], cur[NEXP];
    const int tid = threadIdx.x;
    if (tid < NEXP) cnt[tid] = 0;
    __syncthreads();
    for (int p = tid; p < NROWS; p += blockDim.x)
        atomicAdd(&cnt[topk_ids[p]], 1);
    __syncthreads();
    if (tid == 0) {
        int acc = 0, mb = 0;
        for (int e = 0; e < NEXP; ++e) {
            off[e] = acc;
            int c = cnt[e];
            for (int m0 = 0; m0 < c; m0 += BM) {
                sched[1 + 3 * mb] = e;
                sched[2 + 3 * mb] = acc + m0;
                sched[3 + 3 * mb] = (c - m0 < BM) ? (c - m0) : BM;
                ++mb;
            }
            acc += c;
        }
        sched[0] = mb;
    }
    if (tid < NEXP) cur[tid] = 0;
    __syncthreads();
    for (int p = tid; p < NROWS; p += blockDim.x) {
        int e = topk_ids[p];
        int slot = off[e] + atomicAdd(&cur[e], 1);
        row_token[slot] = p / TOPK;
        row_w[slot]     = topk_w[p];
    }
}

// ---------------- GEMM1: gathered Xb @ w1_e^T, fused silu*up -> H (bf16) -----
__global__ __launch_bounds__(256, 3)
void gemm1_kernel(const u16* __restrict__ Xb, const float* __restrict__ w1,
                  const int* __restrict__ sched, const int* __restrict__ row_token,
                  u16* __restrict__ H) {
    __shared__ u16 lA[2][BM * BK];   // 2 x 16KB, filled by global_load_lds (linear)
    __shared__ u16 lB[BM * BK];      // 16KB, reg-staged + swizzled

    const int mb = blockIdx.y;
    if (mb >= sched[0]) return;
    const int e    = sched[1 + 3 * mb];
    const int m0   = sched[2 + 3 * mb];
    const int mlen = sched[3 + 3 * mb];
    const int n0   = blockIdx.x * 64;     // gate col base; up col = DFF + n0

    const int tid  = threadIdx.x;
    const int lane = tid & 63;
    const int wave = tid >> 6;
    const int wm = wave >> 1, wn = wave & 1;
    const int lr = lane & 15, lk = lane >> 4;

    // A staging via global_load_lds: 4 issues/thread, 1KB per wave per issue
    const u16* asrc[4];
    int aoff[4];                      // LDS elem offset (wave-uniform)
#pragma unroll
    for (int i = 0; i < 4; ++i) {
        int R = i * 32 + wave * 8 + (lane >> 3);
        int grow = m0 + R; if (grow > NROWS - 1) grow = NROWS - 1;
        int tok = row_token[grow];
        asrc[i] = Xb + (size_t)tok * D_DIM + (lane & 7) * 8;
        aoff[i] = i * 2048 + wave * 512;
    }
    // B staging (f32 -> bf16, reg prefetch): 4 chunks/thread, 8 f32 each
    const float* bptr[4];
    int wroff[4];
#pragma unroll
    for (int i = 0; i < 4; ++i) {
        int chunk = i * 256 + tid;
        int row = chunk >> 3, c8 = chunk & 7;
        int gcol = (row < 64) ? (n0 + row) : (DFF_DIM + n0 + (row - 64));
        bptr[i] = w1 + ((size_t)e * (2 * DFF_DIM) + gcol) * D_DIM + c8 * 8;
        wroff[i] = row * 128 + ((c8 * 16) ^ ((row & 7) << 4));
    }

    f32x4 rb[4][2];
    f32x4 accg[4][2], accu[4][2];
#pragma unroll
    for (int m = 0; m < 4; ++m)
#pragma unroll
        for (int n = 0; n < 2; ++n) {
            accg[m][n] = (f32x4){0.f, 0.f, 0.f, 0.f};
            accu[m][n] = (f32x4){0.f, 0.f, 0.f, 0.f};
        }

    // prologue: tile 0
#pragma unroll
    for (int i = 0; i < 4; ++i) gll16(asrc[i], &lA[0][aoff[i]]);
#pragma unroll
    for (int i = 0; i < 4; ++i) {
        rb[i][0] = *(const f32x4*)(bptr[i]);
        rb[i][1] = *(const f32x4*)(bptr[i] + 4);
    }
#pragma unroll
    for (int i = 0; i < 4; ++i) {
        bf16x8 vb;
#pragma unroll
        for (int j = 0; j < 4; ++j) { vb[j] = (short)f2bf(rb[i][0][j]); vb[j + 4] = (short)f2bf(rb[i][1][j]); }
        *(bf16x8*)((char*)lB + wroff[i]) = vb;
    }
    __syncthreads();   // drains gll(0) + lB writes

    int cur = 0;
    const int KT = D_DIM / BK;   // 32
    for (int kt = 0; kt < KT; ++kt) {
        if (kt + 1 < KT) {
            int k0 = (kt + 1) * BK;
#pragma unroll
            for (int i = 0; i < 4; ++i) gll16(asrc[i] + k0, &lA[cur ^ 1][aoff[i]]);
#pragma unroll
            for (int i = 0; i < 4; ++i) {
                rb[i][0] = *(const f32x4*)(bptr[i] + k0);
                rb[i][1] = *(const f32x4*)(bptr[i] + k0 + 4);
            }
        }
        asm volatile("" ::: "memory");   // pin loads above the MFMA phase
#pragma unroll
        for (int ks = 0; ks < 2; ++ks) {
            const int inner = ks * 64 + lk * 16;
            bf16x8 af[4], bg[2], bu[2];
#pragma unroll
            for (int m = 0; m < 4; ++m)
                af[m] = lds_read8_lin(lA[cur], wm * 64 + m * 16 + lr, inner);
#pragma unroll
            for (int n = 0; n < 2; ++n) {
                bg[n] = lds_read8_swz(lB, wn * 32 + n * 16 + lr, inner);
                bu[n] = lds_read8_swz(lB, 64 + wn * 32 + n * 16 + lr, inner);
            }
#pragma unroll
            for (int m = 0; m < 4; ++m)
#pragma unroll
                for (int n = 0; n < 2; ++n) {
                    accg[m][n] = __builtin_amdgcn_mfma_f32_16x16x32_bf16(af[m], bg[n], accg[m][n], 0, 0, 0);
                    accu[m][n] = __builtin_amdgcn_mfma_f32_16x16x32_bf16(af[m], bu[n], accu[m][n], 0, 0, 0);
                }
        }
        __syncthreads();                 // all waves done reading lB (vmcnt drained too)
        if (kt + 1 < KT) {
#pragma unroll
            for (int i = 0; i < 4; ++i) {
                bf16x8 vb;
#pragma unroll
                for (int j = 0; j < 4; ++j) { vb[j] = (short)f2bf(rb[i][0][j]); vb[j + 4] = (short)f2bf(rb[i][1][j]); }
                *(bf16x8*)((char*)lB + wroff[i]) = vb;
            }
        }
        __syncthreads();
        cur ^= 1;
    }

    // epilogue: h = silu(gate) * up  (C/D: col=lane&15, row=(lane>>4)*4+r)
#pragma unroll
    for (int m = 0; m < 4; ++m)
#pragma unroll
        for (int n = 0; n < 2; ++n)
#pragma unroll
            for (int r = 0; r < 4; ++r) {
                int rloc = wm * 64 + m * 16 + (lane >> 4) * 4 + r;
                if (rloc < mlen) {
                    int col = wn * 32 + n * 16 + lr;
                    float g = accg[m][n][r], u = accu[m][n][r];
                    float h = (g / (1.f + __expf(-g))) * u;
                    H[(size_t)(m0 + rloc) * DFF_DIM + n0 + col] = f2bf(h);
                }
            }
}

// ---------------- GEMM2: H @ w2_e^T, scale by route weight, atomicAdd --------
__global__ __launch_bounds__(256, 3)
void gemm2_kernel(const u16* __restrict__ H, const float* __restrict__ w2,
                  const int* __restrict__ sched, const int* __restrict__ row_token,
                  const float* __restrict__ row_w, float* __restrict__ out) {
    __shared__ u16 lA[2][BM * BK];
    __shared__ u16 lB[BM * BK];

    const int mb = blockIdx.y;
    if (mb >= sched[0]) return;
    const int e    = sched[1 + 3 * mb];
    const int m0   = sched[2 + 3 * mb];
    const int mlen = sched[3 + 3 * mb];
    const int n0   = blockIdx.x * 128;

    const int tid  = threadIdx.x;
    const int lane = tid & 63;
    const int wave = tid >> 6;
    const int wm = wave >> 1, wn = wave & 1;
    const int lr = lane & 15, lk = lane >> 4;

    const u16* asrc[4];
    int aoff[4];
#pragma unroll
    for (int i = 0; i < 4; ++i) {
        int R = i * 32 + wave * 8 + (lane >> 3);
        int grow = m0 + R; if (grow > NROWS - 1) grow = NROWS - 1;
        asrc[i] = H + (size_t)grow * DFF_DIM + (lane & 7) * 8;
        aoff[i] = i * 2048 + wave * 512;
    }
    const float* bptr[4];
    int wroff[4];
#pragma unroll
    for (int i = 0; i < 4; ++i) {
        int chunk = i * 256 + tid;
        int row = chunk >> 3, c8 = chunk & 7;
        bptr[i] = w2 + ((size_t)e * D_DIM + (n0 + row)) * DFF_DIM + c8 * 8;
        wroff[i] = row * 128 + ((c8 * 16) ^ ((row & 7) << 4));
    }

    f32x4 rb[4][2];
    f32x4 acc[4][4];
#pragma unroll
    for (int m = 0; m < 4; ++m)
#pragma unroll
        for (int n = 0; n < 4; ++n) acc[m][n] = (f32x4){0.f, 0.f, 0.f, 0.f};

#pragma unroll
    for (int i = 0; i < 4; ++i) gll16(asrc[i], &lA[0][aoff[i]]);
#pragma unroll
    for (int i = 0; i < 4; ++i) {
        rb[i][0] = *(const f32x4*)(bptr[i]);
        rb[i][1] = *(const f32x4*)(bptr[i] + 4);
    }
#pragma unroll
    for (int i = 0; i < 4; ++i) {
        bf16x8 vb;
#pragma unroll
        for (int j = 0; j < 4; ++j) { vb[j] = (short)f2bf(rb[i][0][j]); vb[j + 4] = (short)f2bf(rb[i][1][j]); }
        *(bf16x8*)((char*)lB + wroff[i]) = vb;
    }
    __syncthreads();

    int cur = 0;
    const int KT = DFF_DIM / BK;   // 16
    for (int kt = 0; kt < KT; ++kt) {
        if (kt + 1 < KT) {
            int k0 = (kt + 1) * BK;
#pragma unroll
            for (int i = 0; i < 4; ++i) gll16(asrc[i] + k0, &lA[cur ^ 1][aoff[i]]);
#pragma unroll
            for (int i = 0; i < 4; ++i) {
                rb[i][0] = *(const f32x4*)(bptr[i] + k0);
                rb[i][1] = *(const f32x4*)(bptr[i] + k0 + 4);
            }
        }
        asm volatile("" ::: "memory");
#pragma unroll
        for (int ks = 0; ks < 2; ++ks) {
            const int inner = ks * 64 + lk * 16;
            bf16x8 af[4], bfr[4];
#pragma unroll
            for (int m = 0; m < 4; ++m)
                af[m] = lds_read8_lin(lA[cur], wm * 64 + m * 16 + lr, inner);
#pragma unroll
            for (int n = 0; n < 4; ++n)
                bfr[n] = lds_read8_swz(lB, wn * 64 + n * 16 + lr, inner);
#pragma unroll
            for (int m = 0; m < 4; ++m)
#pragma unroll
                for (int n = 0; n < 4; ++n)
                    acc[m][n] = __builtin_amdgcn_mfma_f32_16x16x32_bf16(af[m], bfr[n], acc[m][n], 0, 0, 0);
        }
        __syncthreads();
        if (kt + 1 < KT) {
#pragma unroll
            for (int i = 0; i < 4; ++i) {
                bf16x8 vb;
#pragma unroll
                for (int j = 0; j < 4; ++j) { vb[j] = (short)f2bf(rb[i][0][j]); vb[j + 4] = (short)f2bf(rb[i][1][j]); }
                *(bf16x8*)((char*)lB + wroff[i]) = vb;
            }
        }
        __syncthreads();
        cur ^= 1;
    }

#pragma unroll
    for (int m = 0; m < 4; ++m)
#pragma unroll
        for (int n = 0; n < 4; ++n)
#pragma unroll
            for (int r = 0; r < 4; ++r) {
                int rloc = wm * 64 + m * 16 + (lane >> 4) * 4 + r;
                if (rloc < mlen) {
                    int grow = m0 + rloc;
                    int tok  = row_token[grow];
                    float w  = row_w[grow];
                    int col  = wn * 64 + n * 16 + lr;
                    atomicAdd(&out[(size_t)tok * D_DIM + n0 + col], acc[m][n][r] * w);
                }
            }
}

extern "C" void kernel_launch(void* const* d_in, const int* in_sizes, int n_in,
                              void* d_out, int out_size, void* d_ws, size_t ws_size,
                              hipStream_t stream) {
    const float* X  = (const float*)d_in[0];
    const float* w1 = (const float*)d_in[1];
    const float* w2 = (const float*)d_in[2];
    const float* tw = (const float*)d_in[3];
    const int*   ti = (const int*)d_in[4];

    // workspace layout (~16.1 MB total)
    int*   sched     = (int*)d_ws;                                   // 121 ints
    int*   row_token = (int*)((char*)d_ws + 512);                    // 4096 ints
    float* row_w     = (float*)((char*)d_ws + 512 + 4 * NROWS);      // 4096 f32
    u16*   Xb        = (u16*)((char*)d_ws + 65536);                  // 2048x2048 bf16 (8MB)
    u16*   H         = (u16*)((char*)d_ws + 65536 + (size_t)T_TOK * D_DIM * 2); // 4096x1024 bf16 (8MB)

    route_kernel<<<1, 256, 0, stream>>>(ti, tw, sched, row_token, row_w);
    cvt_x_kernel<<<(T_TOK * D_DIM) / (256 * 8), 256, 0, stream>>>(X, Xb);
    hipMemsetAsync(d_out, 0, (size_t)out_size * sizeof(float), stream);
    gemm1_kernel<<<dim3(DFF_DIM / 64, MAX_MB), 256, 0, stream>>>(Xb, w1, sched, row_token, H);
    gemm2_kernel<<<dim3(D_DIM / 128, MAX_MB), 256, 0, stream>>>(H, w2, sched, row_token, row_w, (float*)d_out);
}

// Round 3
// 160.633 us; speedup vs baseline: 1.3202x; 1.0067x over previous
//
#include <hip/hip_runtime.h>
#include <hip/hip_bf16.h>
#include <stdint.h>

typedef __attribute__((ext_vector_type(4))) float f32x4;
typedef __attribute__((ext_vector_type(8))) short bf16x8;
typedef unsigned short u16;

#define T_TOK   2048
#define D_DIM   2048
#define DFF_DIM 1024
#define NEXP    8
#define TOPK    2
#define NROWS   (T_TOK * TOPK)   // 4096
#define BM      128
#define BK      64
#define MAX_MB  40               // sum ceil(Mg/128) <= 4096/128 + 7 = 39
#define NBLK1   16               // gemm1 n-blocks (DFF/64)
#define NBLK2   16               // gemm2 n-blocks (D/128)
#define GRID_G  (NBLK1 * MAX_MB) // 640 = 8 * 80

__device__ __forceinline__ u16 f2bf(float f) {
    __hip_bfloat16 h = __float2bfloat16(f);   // RNE; compiler emits v_cvt_pk_bf16_f32
    return *reinterpret_cast<u16*>(&h);
}

__device__ __forceinline__ void gll16(const u16* gsrc, const u16* lds) {
    // async global->LDS, 16B/lane; LDS dest = wave-uniform base + lane*16 (linear)
    __builtin_amdgcn_global_load_lds(
        (const __attribute__((address_space(1))) uint32_t*)gsrc,
        (__attribute__((address_space(3))) uint32_t*)lds, 16, 0, 0);
}

// tile is [128 rows][64 bf16 = 128 B]; XOR-swizzled content (both A and B)
__device__ __forceinline__ bf16x8 lds_read8_swz(const u16* base, int row, int inner) {
    int off = row * 128 + (inner ^ ((row & 7) << 4));
    return *(const bf16x8*)((const char*)base + off);
}

// ---------------- X -> bf16 prepass ------------------------------------------
__global__ void cvt_x_kernel(const float* __restrict__ X, u16* __restrict__ Xb) {
    int idx = (blockIdx.x * 256 + threadIdx.x) * 8;
    f32x4 a = *(const f32x4*)(X + idx);
    f32x4 b = *(const f32x4*)(X + idx + 4);
    bf16x8 v;
#pragma unroll
    for (int j = 0; j < 4; ++j) { v[j] = (short)f2bf(a[j]); v[j + 4] = (short)f2bf(b[j]); }
    *(bf16x8*)(Xb + idx) = v;
}

// ---------------- routing: bucket (token,k) pairs by expert ------------------
__global__ void route_kernel(const int* __restrict__ topk_ids,
                             const float* __restrict__ topk_w,
                             int* __restrict__ sched,        // [0]=nmb, then {e,m0,mlen}*
                             int* __restrict__ row_token,
                             float* __restrict__ row_w) {
    __shared__ int cnt[NEXP], off[NEXP], cur[NEXP];
    const int tid = threadIdx.x;
    if (tid < NEXP) cnt[tid] = 0;
    __syncthreads();
    for (int p = tid; p < NROWS; p += blockDim.x)
        atomicAdd(&cnt[topk_ids[p]], 1);
    __syncthreads();
    if (tid == 0) {
        int acc = 0, mb = 0;
        for (int e = 0; e < NEXP; ++e) {
            off[e] = acc;
            int c = cnt[e];
            for (int m0 = 0; m0 < c; m0 += BM) {
                sched[1 + 3 * mb] = e;
                sched[2 + 3 * mb] = acc + m0;
                sched[3 + 3 * mb] = (c - m0 < BM) ? (c - m0) : BM;
                ++mb;
            }
            acc += c;
        }
        sched[0] = mb;
    }
    if (tid < NEXP) cur[tid] = 0;
    __syncthreads();
    for (int p = tid; p < NROWS; p += blockDim.x) {
        int e = topk_ids[p];
        int slot = off[e] + atomicAdd(&cur[e], 1);
        row_token[slot] = p / TOPK;
        row_w[slot]     = topk_w[p];
    }
}

// ---------------- GEMM1: gathered Xb @ w1_e^T, fused silu*up -> H (bf16) -----
__global__ __launch_bounds__(256, 3)
void gemm1_kernel(const u16* __restrict__ Xb, const float* __restrict__ w1,
                  const int* __restrict__ sched, const int* __restrict__ row_token,
                  u16* __restrict__ H) {
    __shared__ u16 lA[2][BM * BK];   // 2 x 16KB, global_load_lds (linear dest, swz src)
    __shared__ u16 lB[BM * BK];      // 16KB, reg-staged + swizzled

    // XCD-aware swizzle: 640 = 8 XCDs x 80; each XCD gets 5 M-blocks x 16 n-blocks
    const int bid = blockIdx.x;
    const int swz = (bid & 7) * (GRID_G / 8) + (bid >> 3);
    const int mb  = swz >> 4;
    if (mb >= sched[0]) return;
    const int e    = sched[1 + 3 * mb];
    const int m0   = sched[2 + 3 * mb];
    const int mlen = sched[3 + 3 * mb];
    const int n0   = (swz & 15) * 64;   // gate col base; up col = DFF + n0

    const int tid  = threadIdx.x;
    const int lane = tid & 63;
    const int wave = tid >> 6;
    const int wm = wave >> 1, wn = wave & 1;
    const int lr = lane & 15, lk = lane >> 4;

    // A staging via gll: 4 issues/thread; source column XOR-swizzled by row
    const u16* asrc[4];
    int aoff[4];                      // LDS elem offset (wave-uniform)
#pragma unroll
    for (int i = 0; i < 4; ++i) {
        int R = i * 32 + wave * 8 + (lane >> 3);
        int grow = m0 + R; if (grow > NROWS - 1) grow = NROWS - 1;
        int tok = row_token[grow];
        asrc[i] = Xb + (size_t)tok * D_DIM + (size_t)(((lane & 7) ^ (R & 7)) * 8);
        aoff[i] = i * 2048 + wave * 512;
    }
    // B staging (f32 -> bf16, reg prefetch): 4 chunks/thread, 8 f32 each
    const float* bptr[4];
    int wroff[4];
#pragma unroll
    for (int i = 0; i < 4; ++i) {
        int chunk = i * 256 + tid;
        int row = chunk >> 3, c8 = chunk & 7;
        int gcol = (row < 64) ? (n0 + row) : (DFF_DIM + n0 + (row - 64));
        bptr[i] = w1 + ((size_t)e * (2 * DFF_DIM) + gcol) * D_DIM + c8 * 8;
        wroff[i] = row * 128 + ((c8 * 16) ^ ((row & 7) << 4));
    }

    f32x4 rb[4][2];
    f32x4 accg[4][2], accu[4][2];
#pragma unroll
    for (int m = 0; m < 4; ++m)
#pragma unroll
        for (int n = 0; n < 2; ++n) {
            accg[m][n] = (f32x4){0.f, 0.f, 0.f, 0.f};
            accu[m][n] = (f32x4){0.f, 0.f, 0.f, 0.f};
        }

    // prologue: tile 0
#pragma unroll
    for (int i = 0; i < 4; ++i) gll16(asrc[i], &lA[0][aoff[i]]);
#pragma unroll
    for (int i = 0; i < 4; ++i) {
        rb[i][0] = *(const f32x4*)(bptr[i]);
        rb[i][1] = *(const f32x4*)(bptr[i] + 4);
    }
#pragma unroll
    for (int i = 0; i < 4; ++i) {
        bf16x8 vb;
#pragma unroll
        for (int j = 0; j < 4; ++j) { vb[j] = (short)f2bf(rb[i][0][j]); vb[j + 4] = (short)f2bf(rb[i][1][j]); }
        *(bf16x8*)((char*)lB + wroff[i]) = vb;
    }
    __syncthreads();   // drains gll(0) + lB writes

    int cur = 0;
    const int KT = D_DIM / BK;   // 32
    for (int kt = 0; kt < KT; ++kt) {
        if (kt + 1 < KT) {
            int k0 = (kt + 1) * BK;
#pragma unroll
            for (int i = 0; i < 4; ++i) gll16(asrc[i] + k0, &lA[cur ^ 1][aoff[i]]);
#pragma unroll
            for (int i = 0; i < 4; ++i) {
                rb[i][0] = *(const f32x4*)(bptr[i] + k0);
                rb[i][1] = *(const f32x4*)(bptr[i] + k0 + 4);
            }
        }
        asm volatile("" ::: "memory");   // pin loads above the MFMA phase
#pragma unroll
        for (int ks = 0; ks < 2; ++ks) {
            const int inner = ks * 64 + lk * 16;
            bf16x8 af[4], bg[2], bu[2];
#pragma unroll
            for (int m = 0; m < 4; ++m)
                af[m] = lds_read8_swz(lA[cur], wm * 64 + m * 16 + lr, inner);
#pragma unroll
            for (int n = 0; n < 2; ++n) {
                bg[n] = lds_read8_swz(lB, wn * 32 + n * 16 + lr, inner);
                bu[n] = lds_read8_swz(lB, 64 + wn * 32 + n * 16 + lr, inner);
            }
#pragma unroll
            for (int m = 0; m < 4; ++m)
#pragma unroll
                for (int n = 0; n < 2; ++n) {
                    accg[m][n] = __builtin_amdgcn_mfma_f32_16x16x32_bf16(af[m], bg[n], accg[m][n], 0, 0, 0);
                    accu[m][n] = __builtin_amdgcn_mfma_f32_16x16x32_bf16(af[m], bu[n], accu[m][n], 0, 0, 0);
                }
        }
        __syncthreads();                 // all waves done reading lB
        if (kt + 1 < KT) {
#pragma unroll
            for (int i = 0; i < 4; ++i) {
                bf16x8 vb;
#pragma unroll
                for (int j = 0; j < 4; ++j) { vb[j] = (short)f2bf(rb[i][0][j]); vb[j + 4] = (short)f2bf(rb[i][1][j]); }
                *(bf16x8*)((char*)lB + wroff[i]) = vb;
            }
        }
        __syncthreads();
        cur ^= 1;
    }

    // epilogue: h = silu(gate) * up  (C/D: col=lane&15, row=(lane>>4)*4+r)
#pragma unroll
    for (int m = 0; m < 4; ++m)
#pragma unroll
        for (int n = 0; n < 2; ++n)
#pragma unroll
            for (int r = 0; r < 4; ++r) {
                int rloc = wm * 64 + m * 16 + (lane >> 4) * 4 + r;
                if (rloc < mlen) {
                    int col = wn * 32 + n * 16 + lr;
                    float g = accg[m][n][r], u = accu[m][n][r];
                    float h = (g / (1.f + __expf(-g))) * u;
                    H[(size_t)(m0 + rloc) * DFF_DIM + n0 + col] = f2bf(h);
                }
            }
}

// ---------------- GEMM2: H @ w2_e^T, scale by route weight, atomicAdd --------
__global__ __launch_bounds__(256, 3)
void gemm2_kernel(const u16* __restrict__ H, const float* __restrict__ w2,
                  const int* __restrict__ sched, const int* __restrict__ row_token,
                  const float* __restrict__ row_w, float* __restrict__ out) {
    __shared__ u16 lA[2][BM * BK];
    __shared__ u16 lB[BM * BK];

    const int bid = blockIdx.x;
    const int swz = (bid & 7) * (GRID_G / 8) + (bid >> 3);
    const int mb  = swz >> 4;
    if (mb >= sched[0]) return;
    const int e    = sched[1 + 3 * mb];
    const int m0   = sched[2 + 3 * mb];
    const int mlen = sched[3 + 3 * mb];
    const int n0   = (swz & 15) * 128;

    const int tid  = threadIdx.x;
    const int lane = tid & 63;
    const int wave = tid >> 6;
    const int wm = wave >> 1, wn = wave & 1;
    const int lr = lane & 15, lk = lane >> 4;

    const u16* asrc[4];
    int aoff[4];
#pragma unroll
    for (int i = 0; i < 4; ++i) {
        int R = i * 32 + wave * 8 + (lane >> 3);
        int grow = m0 + R; if (grow > NROWS - 1) grow = NROWS - 1;
        asrc[i] = H + (size_t)grow * DFF_DIM + (size_t)(((lane & 7) ^ (R & 7)) * 8);
        aoff[i] = i * 2048 + wave * 512;
    }
    const float* bptr[4];
    int wroff[4];
#pragma unroll
    for (int i = 0; i < 4; ++i) {
        int chunk = i * 256 + tid;
        int row = chunk >> 3, c8 = chunk & 7;
        bptr[i] = w2 + ((size_t)e * D_DIM + (n0 + row)) * DFF_DIM + c8 * 8;
        wroff[i] = row * 128 + ((c8 * 16) ^ ((row & 7) << 4));
    }

    f32x4 rb[4][2];
    f32x4 acc[4][4];
#pragma unroll
    for (int m = 0; m < 4; ++m)
#pragma unroll
        for (int n = 0; n < 4; ++n) acc[m][n] = (f32x4){0.f, 0.f, 0.f, 0.f};

#pragma unroll
    for (int i = 0; i < 4; ++i) gll16(asrc[i], &lA[0][aoff[i]]);
#pragma unroll
    for (int i = 0; i < 4; ++i) {
        rb[i][0] = *(const f32x4*)(bptr[i]);
        rb[i][1] = *(const f32x4*)(bptr[i] + 4);
    }
#pragma unroll
    for (int i = 0; i < 4; ++i) {
        bf16x8 vb;
#pragma unroll
        for (int j = 0; j < 4; ++j) { vb[j] = (short)f2bf(rb[i][0][j]); vb[j + 4] = (short)f2bf(rb[i][1][j]); }
        *(bf16x8*)((char*)lB + wroff[i]) = vb;
    }
    __syncthreads();

    int cur = 0;
    const int KT = DFF_DIM / BK;   // 16
    for (int kt = 0; kt < KT; ++kt) {
        if (kt + 1 < KT) {
            int k0 = (kt + 1) * BK;
#pragma unroll
            for (int i = 0; i < 4; ++i) gll16(asrc[i] + k0, &lA[cur ^ 1][aoff[i]]);
#pragma unroll
            for (int i = 0; i < 4; ++i) {
                rb[i][0] = *(const f32x4*)(bptr[i] + k0);
                rb[i][1] = *(const f32x4*)(bptr[i] + k0 + 4);
            }
        }
        asm volatile("" ::: "memory");
#pragma unroll
        for (int ks = 0; ks < 2; ++ks) {
            const int inner = ks * 64 + lk * 16;
            bf16x8 af[4], bfr[4];
#pragma unroll
            for (int m = 0; m < 4; ++m)
                af[m] = lds_read8_swz(lA[cur], wm * 64 + m * 16 + lr, inner);
#pragma unroll
            for (int n = 0; n < 4; ++n)
                bfr[n] = lds_read8_swz(lB, wn * 64 + n * 16 + lr, inner);
#pragma unroll
            for (int m = 0; m < 4; ++m)
#pragma unroll
                for (int n = 0; n < 4; ++n)
                    acc[m][n] = __builtin_amdgcn_mfma_f32_16x16x32_bf16(af[m], bfr[n], acc[m][n], 0, 0, 0);
        }
        __syncthreads();
        if (kt + 1 < KT) {
#pragma unroll
            for (int i = 0; i < 4; ++i) {
                bf16x8 vb;
#pragma unroll
                for (int j = 0; j < 4; ++j) { vb[j] = (short)f2bf(rb[i][0][j]); vb[j + 4] = (short)f2bf(rb[i][1][j]); }
                *(bf16x8*)((char*)lB + wroff[i]) = vb;
            }
        }
        __syncthreads();
        cur ^= 1;
    }

#pragma unroll
    for (int m = 0; m < 4; ++m)
#pragma unroll
        for (int n = 0; n < 4; ++n)
#pragma unroll
            for (int r = 0; r < 4; ++r) {
                int rloc = wm * 64 + m * 16 + (lane >> 4) * 4 + r;
                if (rloc < mlen) {
                    int grow = m0 + rloc;
                    int tok  = row_token[grow];
                    float w  = row_w[grow];
                    int col  = wn * 64 + n * 16 + lr;
                    atomicAdd(&out[(size_t)tok * D_DIM + n0 + col], acc[m][n][r] * w);
                }
            }
}

extern "C" void kernel_launch(void* const* d_in, const int* in_sizes, int n_in,
                              void* d_out, int out_size, void* d_ws, size_t ws_size,
                              hipStream_t stream) {
    const float* X  = (const float*)d_in[0];
    const float* w1 = (const float*)d_in[1];
    const float* w2 = (const float*)d_in[2];
    const float* tw = (const float*)d_in[3];
    const int*   ti = (const int*)d_in[4];

    // workspace layout (~16.1 MB total)
    int*   sched     = (int*)d_ws;                                   // 121 ints
    int*   row_token = (int*)((char*)d_ws + 512);                    // 4096 ints
    float* row_w     = (float*)((char*)d_ws + 512 + 4 * NROWS);      // 4096 f32
    u16*   Xb        = (u16*)((char*)d_ws + 65536);                  // 2048x2048 bf16 (8MB)
    u16*   H         = (u16*)((char*)d_ws + 65536 + (size_t)T_TOK * D_DIM * 2); // 4096x1024 bf16 (8MB)

    route_kernel<<<1, 256, 0, stream>>>(ti, tw, sched, row_token, row_w);
    cvt_x_kernel<<<(T_TOK * D_DIM) / (256 * 8), 256, 0, stream>>>(X, Xb);
    hipMemsetAsync(d_out, 0, (size_t)out_size * sizeof(float), stream);
    gemm1_kernel<<<GRID_G, 256, 0, stream>>>(Xb, w1, sched, row_token, H);
    gemm2_kernel<<<GRID_G, 256, 0, stream>>>(H, w2, sched, row_token, row_w, (float*)d_out);
}